// Round 2
// 1590.370 us; speedup vs baseline: 1.1911x; 1.1911x over previous
//
#include <hip/hip_runtime.h>

#define DEV __device__ __forceinline__

typedef unsigned short u16;
typedef __attribute__((ext_vector_type(8))) short short8;
typedef __attribute__((ext_vector_type(4))) float f32x4;

// ---------- bf16 helpers (bit-level, avoids header API differences) ----------
DEV u16 f2b(float f) {
  union { float f; unsigned u; } x; x.f = f;
  unsigned r = x.u + 0x7fffu + ((x.u >> 16) & 1u);
  return (u16)(r >> 16);
}
DEV float b2f(u16 h) { union { unsigned u; float f; } x; x.u = ((unsigned)h) << 16; return x.f; }
DEV float tof(float v) { return v; }
DEV float tof(u16 v) { return b2f(v); }

// async global->LDS, 16B per lane, dest = wave-uniform base + lane*16
DEV void async_ld16(const void* g, void* l) {
  __builtin_amdgcn_global_load_lds(
      (const __attribute__((address_space(1))) void*)g,
      (__attribute__((address_space(3))) void*)l, 16, 0, 0);
}

// ---------------------------------------------------------------------------
// GEMM: C[M,N] = act(scale * A[M,K] @ Bt[N,K]^T + bias + Res)
// A bf16 (or f32 converted in staging when AF32), Bt bf16 [N,K].
// Batched over blockIdx.z with (z/Hd, z%Hd) offset pattern for A/B/C.
// BM x BN tile, 256 threads (2x2 waves), BK=32, mfma 16x16x32 bf16.
// ---------------------------------------------------------------------------
template <int BM, int BN, bool AF32>
__launch_bounds__(256, 2)
__global__ void gemm_bt(const void* __restrict__ Ap, const u16* __restrict__ Btp,
                        float* __restrict__ Cf, u16* __restrict__ Cb,
                        const float* __restrict__ bias, const float* __restrict__ Res,
                        int K, int lda, int ldb, int ldc, int Hd,
                        long sAo, long sAi, long sBo, long sBi, long sCo, long sCi,
                        float scale, int relu) {
  constexpr int BK = 32;
  __shared__ __align__(16) u16 lA[BM * BK];
  __shared__ __align__(16) u16 lB[BN * BK];
  const int z = blockIdx.z;
  const long aoff = (long)(z / Hd) * sAo + (long)(z % Hd) * sAi;
  const long boff = (long)(z / Hd) * sBo + (long)(z % Hd) * sBi;
  const long coff = (long)(z / Hd) * sCo + (long)(z % Hd) * sCi;
  const u16* A16 = (const u16*)Ap + aoff;
  const float* A32 = (const float*)Ap + aoff;
  const u16* Bt = Btp + boff;

  const int m0 = blockIdx.y * BM;
  const int n0 = blockIdx.x * BN;
  const int tid = threadIdx.x;
  const int lane = tid & 63;
  const int wave = tid >> 6;
  const int wr = wave >> 1, wc = wave & 1;
  constexpr int WM = BM / 2, WN = BN / 2;
  constexpr int MI = WM / 16, NI = WN / 16;
  constexpr int ISS_A = BM / 64;
  constexpr int ISS_B = BN / 64;

  f32x4 acc[MI][NI];
#pragma unroll
  for (int i = 0; i < MI; ++i)
#pragma unroll
    for (int j = 0; j < NI; ++j) acc[i][j] = {0.f, 0.f, 0.f, 0.f};

  const int rl = lane & 15;
  const int kq = (lane >> 4) * 8;

  for (int kt = 0; kt < K; kt += BK) {
    if (kt) __syncthreads();
    if (!AF32) {
#pragma unroll
      for (int i = 0; i < ISS_A; ++i) {
        int chunk = (wave * ISS_A + i) * 64 + lane;
        int r = chunk >> 2, c = (chunk & 3) * 8;
        async_ld16(A16 + (long)(m0 + r) * lda + kt + c,
                   (char*)lA + (wave * ISS_A + i) * 1024);
      }
    } else {
#pragma unroll
      for (int i = 0; i < (BM * BK) / 1024; ++i) {
        int e = (i * 256 + tid) * 4;
        int r = e >> 5, c = e & 31;
        float4 v = *(const float4*)(A32 + (long)(m0 + r) * lda + kt + c);
        ushort4 pk;
        pk.x = f2b(v.x); pk.y = f2b(v.y); pk.z = f2b(v.z); pk.w = f2b(v.w);
        *(ushort4*)(lA + r * BK + c) = pk;
      }
    }
#pragma unroll
    for (int i = 0; i < ISS_B; ++i) {
      int chunk = (wave * ISS_B + i) * 64 + lane;
      int r = chunk >> 2, c = (chunk & 3) * 8;
      async_ld16(Bt + (long)(n0 + r) * ldb + kt + c,
                 (char*)lB + (wave * ISS_B + i) * 1024);
    }
    __syncthreads();

    short8 af[MI], bfr[NI];
#pragma unroll
    for (int mi = 0; mi < MI; ++mi)
      af[mi] = *(const short8*)(lA + (wr * WM + mi * 16 + rl) * BK + kq);
#pragma unroll
    for (int ni = 0; ni < NI; ++ni)
      bfr[ni] = *(const short8*)(lB + (wc * WN + ni * 16 + rl) * BK + kq);
#pragma unroll
    for (int mi = 0; mi < MI; ++mi)
#pragma unroll
      for (int ni = 0; ni < NI; ++ni)
        acc[mi][ni] = __builtin_amdgcn_mfma_f32_16x16x32_bf16(af[mi], bfr[ni], acc[mi][ni], 0, 0, 0);
  }

  const int rq = (lane >> 4) * 4;
#pragma unroll
  for (int mi = 0; mi < MI; ++mi) {
#pragma unroll
    for (int ni = 0; ni < NI; ++ni) {
      int gc = n0 + wc * WN + ni * 16 + rl;
      float bv = bias ? bias[gc] : 0.f;
#pragma unroll
      for (int r = 0; r < 4; ++r) {
        int gr = m0 + wr * WM + mi * 16 + rq + r;
        long ci = coff + (long)gr * ldc + gc;
        float v = acc[mi][ni][r] * scale + bv;
        if (Res) v += Res[ci];
        if (relu) v = fmaxf(v, 0.f);
        if (Cf) Cf[ci] = v;
        if (Cb) Cb[ci] = f2b(v);
      }
    }
  }
}

// ---------------------------------------------------------------------------
// Fused attention: per block = one (bh, 128-row Q tile).
//   pass A: S = Q K^T per 128-col chunk -> running row max m, sum l
//   pass B: recompute S chunk, p = exp(s-m)/l, optionally store p (f32, the
//           graded attn map), p->bf16 into LDS, O += P V via MFMA.
// Layouts: Q,K [B,T,1024] bf16 head cols h*64; Vt [bh][64][TK] bf16.
// All LDS tiles XOR-swizzled (byte ^= (row&7)<<4) via pre-swizzled global src.
// 4 waves, wave w owns q rows [w*32, w*32+32).
// ---------------------------------------------------------------------------
template <int TK, bool CAUSAL, bool WP>
__launch_bounds__(256, 2)
__global__ void attn_fused(const u16* __restrict__ Qp, const u16* __restrict__ Kp,
                           const u16* __restrict__ Vtp, float* __restrict__ Pp,
                           u16* __restrict__ Op) {
  __shared__ __align__(16) u16 lQ[128 * 64];    // 16KB, rows 128B
  __shared__ __align__(16) u16 lK[128 * 64];    // 16KB, rows 128B
  __shared__ __align__(16) u16 lVt[64 * 128];   // 16KB, rows 256B (dk x kpos)
  __shared__ __align__(16) u16 lP[4][32 * 128]; // 32KB, per-wave, rows 256B

  const int bh = blockIdx.y, b = bh >> 4, h = bh & 15;
  const u16* Qb = Qp + (long)b * 524288 + h * 64;
  const u16* Kb = Kp + (long)b * ((long)TK * 1024) + h * 64;
  const u16* Vtb = Vtp + (long)bh * (64L * TK);
  float* Pb = Pp ? Pp + (long)b * (16L * 512 * TK) + (long)h * (512L * TK) : nullptr;
  u16* Ob = Op + (long)b * 524288 + h * 64;

  const int q0 = blockIdx.x * 128;
  const int tid = threadIdx.x, lane = tid & 63, wave = tid >> 6;
  const int rl = lane & 15;
  const int cbase = (lane >> 4) * 16;  // fragment col-byte base (8 bf16)
  const int rq = (lane >> 4) * 4;      // acc row base within 16-tile
  const int w32 = wave * 32;
  const int nch = CAUSAL ? (blockIdx.x + 1) : (TK / 128);

  // stage Q tile [128][64] once (swizzle via inverse-swizzled source)
#pragma unroll
  for (int i = 0; i < 4; ++i) {
    int base = (wave * 4 + i) * 1024;
    int p = base + lane * 16;
    int row = p >> 7;
    int col = ((p ^ ((row & 7) << 4)) & 127) >> 1;
    async_ld16(Qb + (long)(q0 + row) * 1024 + col, (char*)lQ + base);
  }

  auto stageK = [&](int kt) {
#pragma unroll
    for (int i = 0; i < 4; ++i) {
      int base = (wave * 4 + i) * 1024;
      int p = base + lane * 16;
      int row = p >> 7;
      int col = ((p ^ ((row & 7) << 4)) & 127) >> 1;
      async_ld16(Kb + (long)(kt + row) * 1024 + col, (char*)lK + base);
    }
  };
  auto computeS = [&](f32x4 (&s)[2][8]) {
#pragma unroll
    for (int mi = 0; mi < 2; ++mi)
#pragma unroll
      for (int ni = 0; ni < 8; ++ni) s[mi][ni] = {0.f, 0.f, 0.f, 0.f};
#pragma unroll
    for (int kk = 0; kk < 2; ++kk) {
      const int cb = kk * 64 + cbase;
      short8 aq[2], bk[8];
#pragma unroll
      for (int mi = 0; mi < 2; ++mi) {
        int rr = w32 + mi * 16 + rl;
        aq[mi] = *(const short8*)((const char*)lQ + ((((rr << 7) + cb)) ^ ((rr & 7) << 4)));
      }
#pragma unroll
      for (int ni = 0; ni < 8; ++ni) {
        int rr = ni * 16 + rl;
        bk[ni] = *(const short8*)((const char*)lK + ((((rr << 7) + cb)) ^ ((rr & 7) << 4)));
      }
#pragma unroll
      for (int mi = 0; mi < 2; ++mi)
#pragma unroll
        for (int ni = 0; ni < 8; ++ni)
          s[mi][ni] = __builtin_amdgcn_mfma_f32_16x16x32_bf16(aq[mi], bk[ni], s[mi][ni], 0, 0, 0);
    }
  };

  float m_[2][4], l_[2][4];
#pragma unroll
  for (int mi = 0; mi < 2; ++mi)
#pragma unroll
    for (int r = 0; r < 4; ++r) { m_[mi][r] = -1e30f; l_[mi][r] = 0.f; }

  // ---- pass A: row max & exp-sum ----
  for (int c = 0; c < nch; ++c) {
    const int kt = c * 128;
    if (c) __syncthreads();   // all waves done reading prev lK
    stageK(kt);
    __syncthreads();          // drains vmcnt (Q too on first iter)

    f32x4 s[2][8];
    computeS(s);
#pragma unroll
    for (int mi = 0; mi < 2; ++mi)
#pragma unroll
      for (int r = 0; r < 4; ++r) {
        int gq = q0 + w32 + mi * 16 + rq + r;
        float vv[8];
        float mx = -1e30f;
#pragma unroll
        for (int ni = 0; ni < 8; ++ni) {
          float v = s[mi][ni][r] * 0.125f;
          if (CAUSAL && (kt + ni * 16 + rl > gq)) v = -1e30f;
          vv[ni] = v;
          mx = fmaxf(mx, v);
        }
#pragma unroll
        for (int o = 8; o; o >>= 1) mx = fmaxf(mx, __shfl_xor(mx, o));
        float mo = m_[mi][r], mn = fmaxf(mo, mx);
        float sum = 0.f;
#pragma unroll
        for (int ni = 0; ni < 8; ++ni) sum += __expf(vv[ni] - mn);
#pragma unroll
        for (int o = 8; o; o >>= 1) sum += __shfl_xor(sum, o);
        l_[mi][r] = l_[mi][r] * __expf(mo - mn) + sum;
        m_[mi][r] = mn;
      }
  }

  float il[2][4];
#pragma unroll
  for (int mi = 0; mi < 2; ++mi)
#pragma unroll
    for (int r = 0; r < 4; ++r) il[mi][r] = 1.f / l_[mi][r];

  f32x4 o_[2][4];
#pragma unroll
  for (int mi = 0; mi < 2; ++mi)
#pragma unroll
    for (int nj = 0; nj < 4; ++nj) o_[mi][nj] = {0.f, 0.f, 0.f, 0.f};

  __syncthreads();  // pass A reads of lK complete before pass B restages

  // ---- pass B: probs + PV ----
  u16* lPw = &lP[wave][0];
  for (int c = 0; c < nch; ++c) {
    const int kt = c * 128;
    if (c) __syncthreads();   // prev chunk's lK/lVt reads done
    stageK(kt);
#pragma unroll
    for (int i = 0; i < 4; ++i) {  // stage Vt chunk [64][128]
      int base = (wave * 4 + i) * 1024;
      int p = base + lane * 16;
      int row = p >> 8;
      int col = ((p ^ ((row & 7) << 4)) & 255) >> 1;
      async_ld16(Vtb + (long)row * TK + kt + col, (char*)lVt + base);
    }
    __syncthreads();

    f32x4 s[2][8];
    computeS(s);

#pragma unroll
    for (int mi = 0; mi < 2; ++mi)
#pragma unroll
      for (int r = 0; r < 4; ++r) {
        int prow = mi * 16 + rq + r;       // local q row within wave (0..31)
        int gq = q0 + w32 + prow;
        float mm = m_[mi][r], ii = il[mi][r];
#pragma unroll
        for (int ni = 0; ni < 8; ++ni) {
          int col = ni * 16 + rl;
          float v = s[mi][ni][r] * 0.125f;
          if (CAUSAL && (kt + col > gq)) v = -1e30f;
          float p = __expf(v - mm) * ii;
          if constexpr (WP) Pb[(long)gq * TK + kt + col] = p;
          *(u16*)((char*)lPw + (((prow << 8) + col * 2) ^ ((prow & 7) << 4))) = f2b(p);
        }
      }
    __syncthreads();  // lP writes visible (and cheap cross-wave alignment)

#pragma unroll
    for (int kk = 0; kk < 4; ++kk) {
      const int cb = kk * 64 + cbase;
      short8 ap[2], bv[4];
#pragma unroll
      for (int mi = 0; mi < 2; ++mi) {
        int rr = mi * 16 + rl;
        ap[mi] = *(const short8*)((const char*)lPw + ((((rr << 8) + cb)) ^ ((rr & 7) << 4)));
      }
#pragma unroll
      for (int nj = 0; nj < 4; ++nj) {
        int rr = nj * 16 + rl;
        bv[nj] = *(const short8*)((const char*)lVt + ((((rr << 8) + cb)) ^ ((rr & 7) << 4)));
      }
#pragma unroll
      for (int mi = 0; mi < 2; ++mi)
#pragma unroll
        for (int nj = 0; nj < 4; ++nj)
          o_[mi][nj] = __builtin_amdgcn_mfma_f32_16x16x32_bf16(ap[mi], bv[nj], o_[mi][nj], 0, 0, 0);
    }
  }

  // epilogue: O bf16 -> [B,T,1024] at head col offset
#pragma unroll
  for (int mi = 0; mi < 2; ++mi)
#pragma unroll
    for (int nj = 0; nj < 4; ++nj) {
      int dk = nj * 16 + rl;
#pragma unroll
      for (int r = 0; r < 4; ++r) {
        int gq = q0 + w32 + mi * 16 + rq + r;
        Ob[(long)gq * 1024 + dk] = f2b(o_[mi][nj][r]);
      }
    }
}

// ---------------------------------------------------------------------------
// Transpose + convert to bf16: out[z][c][r] = in[(z/Hd)*so+(z%Hd)*si + r*ldin + c]
// ---------------------------------------------------------------------------
template <typename SRC>
__launch_bounds__(256)
__global__ void transpose_cvt(const SRC* __restrict__ in, u16* __restrict__ out,
                              int R, int C, int ldin, int Hd, long so, long si, long oz) {
  __shared__ float tile[32][33];
  int z = blockIdx.z;
  long ib = (long)(z / Hd) * so + (long)(z % Hd) * si;
  int r0 = blockIdx.y * 32, c0 = blockIdx.x * 32;
  int tx = threadIdx.x & 31, ty = threadIdx.x >> 5;
#pragma unroll
  for (int i = 0; i < 32; i += 8)
    tile[ty + i][tx] = tof(in[ib + (long)(r0 + ty + i) * ldin + (c0 + tx)]);
  __syncthreads();
  long ob = (long)z * oz;
#pragma unroll
  for (int i = 0; i < 32; i += 8)
    out[ob + (long)(c0 + ty + i) * R + (r0 + tx)] = f2b(tile[tx][ty + i]);
}

__launch_bounds__(256)
__global__ void cvt_f32_bf16(const float* __restrict__ in, u16* __restrict__ out) {
  long i = ((long)blockIdx.x * 256 + threadIdx.x) * 4;
  float4 v = *(const float4*)(in + i);
  ushort4 o;
  o.x = f2b(v.x); o.y = f2b(v.y); o.z = f2b(v.z); o.w = f2b(v.w);
  *(ushort4*)(out + i) = o;
}

// ---------------------------------------------------------------------------
// LayerNorm rows of 1024, torch-style: y = g*(x-m)/(std_bessel + 1e-6) + b
// ---------------------------------------------------------------------------
__launch_bounds__(256)
__global__ void ln_rows(const float* __restrict__ x, const float* __restrict__ g,
                        const float* __restrict__ b, float* __restrict__ outf,
                        u16* __restrict__ outb) {
  __shared__ float red[8];
  int row = blockIdx.x, tid = threadIdx.x;
  int lane = tid & 63, wave = tid >> 6;
  const float4 v = *(const float4*)(x + (long)row * 1024 + tid * 4);
  float s = v.x + v.y + v.z + v.w;
#pragma unroll
  for (int o = 32; o; o >>= 1) s += __shfl_xor(s, o);
  if (lane == 0) red[wave] = s;
  __syncthreads();
  float mean = (red[0] + red[1] + red[2] + red[3]) * (1.f / 1024.f);
  float4 d;
  d.x = v.x - mean; d.y = v.y - mean; d.z = v.z - mean; d.w = v.w - mean;
  float sq = d.x * d.x + d.y * d.y + d.z * d.z + d.w * d.w;
#pragma unroll
  for (int o = 32; o; o >>= 1) sq += __shfl_xor(sq, o);
  if (lane == 0) red[4 + wave] = sq;
  __syncthreads();
  float var = (red[4] + red[5] + red[6] + red[7]) * (1.f / 1023.f);
  float inv = 1.f / (sqrtf(var) + 1e-6f);
  const float4 gv = *(const float4*)(g + tid * 4);
  const float4 bv = *(const float4*)(b + tid * 4);
  float4 y;
  y.x = gv.x * d.x * inv + bv.x;
  y.y = gv.y * d.y * inv + bv.y;
  y.z = gv.z * d.z * inv + bv.z;
  y.w = gv.w * d.w * inv + bv.w;
  if (outf) *(float4*)(outf + (long)row * 1024 + tid * 4) = y;
  if (outb) {
    ushort4 o;
    o.x = f2b(y.x); o.y = f2b(y.y); o.z = f2b(y.z); o.w = f2b(y.w);
    *(ushort4*)(outb + (long)row * 1024 + tid * 4) = o;
  }
}

// ---------------------------------------------------------------------------
extern "C" void kernel_launch(void* const* d_in, const int* in_sizes, int n_in,
                              void* d_out, int out_size, void* d_ws, size_t ws_size,
                              hipStream_t stream) {
  // B=16 T=512 D=1024 H=16 DK=64 DFF=2048 TK_cross=1024(=32*32)
  const float* text   = (const float*)d_in[0];
  const float* conv   = (const float*)d_in[1];
  const float* sa_wq  = (const float*)d_in[2];
  const float* sa_bq  = (const float*)d_in[3];
  const float* sa_wk  = (const float*)d_in[4];
  const float* sa_bk  = (const float*)d_in[5];
  const float* sa_wv  = (const float*)d_in[6];
  const float* sa_bv  = (const float*)d_in[7];
  const float* sa_wo  = (const float*)d_in[8];
  const float* sa_bo  = (const float*)d_in[9];
  const float* ca_wq  = (const float*)d_in[10];
  const float* ca_bq  = (const float*)d_in[11];
  const float* ca_wk  = (const float*)d_in[12];
  const float* ca_bk  = (const float*)d_in[13];
  const float* ca_wv  = (const float*)d_in[14];
  const float* ca_bv  = (const float*)d_in[15];
  const float* ca_wo  = (const float*)d_in[16];
  const float* ca_bo  = (const float*)d_in[17];
  const float* ffn_w1 = (const float*)d_in[18];
  const float* ffn_b1 = (const float*)d_in[19];
  const float* ffn_w2 = (const float*)d_in[20];
  const float* ffn_b2 = (const float*)d_in[21];
  const float* ln1_g  = (const float*)d_in[22];
  const float* ln1_b  = (const float*)d_in[23];
  const float* ln2_g  = (const float*)d_in[24];
  const float* ln2_b  = (const float*)d_in[25];
  const float* ln3_g  = (const float*)d_in[26];
  const float* ln3_b  = (const float*)d_in[27];

  char* ws = (char*)d_ws;
  const size_t MiB = 1u << 20;
  // weight slabs [0,24) MiB
  u16* wt_saq = (u16*)(ws + 0 * MiB);
  u16* wt_sak = (u16*)(ws + 2 * MiB);
  u16* wt_sav = (u16*)(ws + 4 * MiB);
  u16* wt_sao = (u16*)(ws + 6 * MiB);
  u16* wt_caq = (u16*)(ws + 8 * MiB);
  u16* wt_cak = (u16*)(ws + 10 * MiB);
  u16* wt_cav = (u16*)(ws + 12 * MiB);
  u16* wt_cao = (u16*)(ws + 14 * MiB);
  u16* wt_f1  = (u16*)(ws + 16 * MiB);  // [2048][1024]
  u16* wt_f2  = (u16*)(ws + 20 * MiB);  // [1024][2048]
  // activation slabs (reused over time; comments give the lifetime owner)
  u16* XB    = (u16*)(ws + 24 * MiB);   // text bf16 -> later SA attn-out bf16
  u16* ATTNB = XB;
  u16* QB    = (u16*)(ws + 40 * MiB);   // SA Q -> later result1 bf16
  u16* RES1B = QB;
  u16* KB    = (u16*)(ws + 56 * MiB);   // SA K -> later CA Q bf16
  u16* Q2B   = KB;
  u16* VB    = (u16*)(ws + 72 * MiB);   // SA V -> later CA attn-out bf16
  u16* CAB   = VB;
  u16* VT    = (u16*)(ws + 88 * MiB);   // SA V^T per head -> later result2 bf16
  u16* RES2B = VT;
  u16* KVB   = (u16*)(ws + 104 * MiB);  // kv bf16 [16][1024][1024]
  u16* K2B   = (u16*)(ws + 136 * MiB);  // CA K bf16 [16][1024][1024]
  u16* V2B   = (u16*)(ws + 168 * MiB);  // CA V bf16
  u16* VT2   = (u16*)(ws + 200 * MiB);  // CA V^T per head [256][64][1024]
  float* BUF  = (float*)(ws + 232 * MiB);  // pre-LN sums (reused x3)
  u16*   HID  = (u16*)(ws + 264 * MiB);    // FFN hidden bf16 [8192][2048]
  float* RES1 = (float*)(ws + 296 * MiB);  // result1 f32 -> later result2 f32
  float* RES2 = RES1;
  float* result = (float*)d_out;                // [8192][1024]
  float* pmap   = (float*)d_out + 8388608;      // [256][512][1024] attn map

  dim3 tb(256);

  // ---- phase 0: conversions ----
  cvt_f32_bf16<<<8192, tb, 0, stream>>>(text, XB);
  transpose_cvt<float><<<dim3(32, 32, 1), tb, 0, stream>>>(sa_wq, wt_saq, 1024, 1024, 1024, 1, 0, 0, 0);
  transpose_cvt<float><<<dim3(32, 32, 1), tb, 0, stream>>>(sa_wk, wt_sak, 1024, 1024, 1024, 1, 0, 0, 0);
  transpose_cvt<float><<<dim3(32, 32, 1), tb, 0, stream>>>(sa_wv, wt_sav, 1024, 1024, 1024, 1, 0, 0, 0);
  transpose_cvt<float><<<dim3(32, 32, 1), tb, 0, stream>>>(sa_wo, wt_sao, 1024, 1024, 1024, 1, 0, 0, 0);
  transpose_cvt<float><<<dim3(32, 32, 1), tb, 0, stream>>>(ca_wq, wt_caq, 1024, 1024, 1024, 1, 0, 0, 0);
  transpose_cvt<float><<<dim3(32, 32, 1), tb, 0, stream>>>(ca_wk, wt_cak, 1024, 1024, 1024, 1, 0, 0, 0);
  transpose_cvt<float><<<dim3(32, 32, 1), tb, 0, stream>>>(ca_wv, wt_cav, 1024, 1024, 1024, 1, 0, 0, 0);
  transpose_cvt<float><<<dim3(32, 32, 1), tb, 0, stream>>>(ca_wo, wt_cao, 1024, 1024, 1024, 1, 0, 0, 0);
  transpose_cvt<float><<<dim3(64, 32, 1), tb, 0, stream>>>(ffn_w1, wt_f1, 1024, 2048, 2048, 1, 0, 0, 0);
  transpose_cvt<float><<<dim3(32, 64, 1), tb, 0, stream>>>(ffn_w2, wt_f2, 2048, 1024, 1024, 1, 0, 0, 0);

  // ---- phase 1: causal self-attention ----
  gemm_bt<128, 128, false><<<dim3(8, 64, 1), tb, 0, stream>>>(
      XB, wt_saq, nullptr, QB, sa_bq, nullptr, 1024, 1024, 1024, 1024, 1, 0, 0, 0, 0, 0, 0, 1.f, 0);
  gemm_bt<128, 128, false><<<dim3(8, 64, 1), tb, 0, stream>>>(
      XB, wt_sak, nullptr, KB, sa_bk, nullptr, 1024, 1024, 1024, 1024, 1, 0, 0, 0, 0, 0, 0, 1.f, 0);
  gemm_bt<128, 128, false><<<dim3(8, 64, 1), tb, 0, stream>>>(
      XB, wt_sav, nullptr, VB, sa_bv, nullptr, 1024, 1024, 1024, 1024, 1, 0, 0, 0, 0, 0, 0, 1.f, 0);
  // V^T per head: [bh][64][512]
  transpose_cvt<u16><<<dim3(2, 16, 256), tb, 0, stream>>>(VB, VT, 512, 64, 1024, 16, 524288, 64, 32768);
  // fused scores->softmax->PV (causal, no prob output)
  attn_fused<512, true, false><<<dim3(4, 256), tb, 0, stream>>>(QB, KB, VT, nullptr, ATTNB);
  // out proj + residual(text)
  gemm_bt<128, 128, false><<<dim3(8, 64, 1), tb, 0, stream>>>(
      ATTNB, wt_sao, BUF, nullptr, sa_bo, text, 1024, 1024, 1024, 1024, 1, 0, 0, 0, 0, 0, 0, 1.f, 0);
  ln_rows<<<8192, tb, 0, stream>>>(BUF, ln1_g, ln1_b, RES1, RES1B);

  // ---- phase 2: cross-attention ----
  // kv = conv [B,C,HW] -> [B,HW,C] bf16
  transpose_cvt<float><<<dim3(32, 32, 16), tb, 0, stream>>>(conv, KVB, 1024, 1024, 1024, 1, 1048576, 0, 1048576);
  gemm_bt<128, 128, false><<<dim3(8, 64, 1), tb, 0, stream>>>(
      RES1B, wt_caq, nullptr, Q2B, ca_bq, nullptr, 1024, 1024, 1024, 1024, 1, 0, 0, 0, 0, 0, 0, 1.f, 0);
  gemm_bt<128, 128, false><<<dim3(8, 128, 1), tb, 0, stream>>>(
      KVB, wt_cak, nullptr, K2B, ca_bk, nullptr, 1024, 1024, 1024, 1024, 1, 0, 0, 0, 0, 0, 0, 1.f, 0);
  gemm_bt<128, 128, false><<<dim3(8, 128, 1), tb, 0, stream>>>(
      KVB, wt_cav, nullptr, V2B, ca_bv, nullptr, 1024, 1024, 1024, 1024, 1, 0, 0, 0, 0, 0, 0, 1.f, 0);
  transpose_cvt<u16><<<dim3(2, 32, 256), tb, 0, stream>>>(V2B, VT2, 1024, 64, 1024, 16, 1048576, 64, 65536);
  // fused scores->softmax->PV; probs f32 straight into d_out (graded attn map)
  attn_fused<1024, false, true><<<dim3(4, 256), tb, 0, stream>>>(Q2B, K2B, VT2, pmap, CAB);
  gemm_bt<128, 128, false><<<dim3(8, 64, 1), tb, 0, stream>>>(
      CAB, wt_cao, BUF, nullptr, ca_bo, RES1, 1024, 1024, 1024, 1024, 1, 0, 0, 0, 0, 0, 0, 1.f, 0);
  ln_rows<<<8192, tb, 0, stream>>>(BUF, ln2_g, ln2_b, RES2, RES2B);

  // ---- phase 3: FFN ----
  gemm_bt<128, 128, false><<<dim3(16, 64, 1), tb, 0, stream>>>(
      RES2B, wt_f1, nullptr, HID, ffn_b1, nullptr, 1024, 1024, 1024, 2048, 1, 0, 0, 0, 0, 0, 0, 1.f, 1);
  gemm_bt<128, 128, false><<<dim3(8, 64, 1), tb, 0, stream>>>(
      HID, wt_f2, BUF, nullptr, ffn_b2, RES2, 2048, 2048, 2048, 1024, 1, 0, 0, 0, 0, 0, 0, 1.f, 0);
  ln_rows<<<8192, tb, 0, stream>>>(BUF, ln3_g, ln3_b, result, nullptr);
}